// Round 3
// baseline (109.145 us; speedup 1.0000x reference)
//
#include <hip/hip_runtime.h>
#include <hip/hip_bf16.h>

// EGNN layer, MI355X. B=4, N=256, H=128, E=16, EIN=273. All I/O float32.
// h1 = pre_i(i) + pre_j(j) + d2*w_d2 + ef@Wef + be1 (layer-1 GEMM collapses to
// per-node precompute + 17x128 per-edge assembly); layer-2 128x128 GEMM via
// mfma_f32_16x16x32_bf16 (h1, We2 rounded to bf16 internally). One thread owns
// one edge row in phase 1 (in-thread LN stats). Deterministic tree reductions.

typedef unsigned short ushort_t;
typedef __attribute__((ext_vector_type(8))) short short8;
typedef __attribute__((ext_vector_type(4))) float f32x4;

__device__ __forceinline__ ushort_t f2bf(float f) {
  unsigned int x = __builtin_bit_cast(unsigned int, f);
  x += 0x7fffu + ((x >> 16) & 1u);
  return (ushort_t)(x >> 16);
}
__device__ __forceinline__ float bf2f(ushort_t u) {
  unsigned int x = ((unsigned int)u) << 16;
  return __builtin_bit_cast(float, x);
}
// if inputs were bf16, mask (all ones) first dword would be 0x3F803F80
__device__ __forceinline__ bool looks_bf16(const float* mk) {
  return __builtin_bit_cast(unsigned int, mk[0]) == 0x3F803F80u;
}

// ---------------- sentinel kernels (diagnostic) ----------------
__global__ void k_sent777(float* out0) { out0[threadIdx.x] = 777.f; }

// ---------------- kernel 1: per-node pre-projections ----------------
// pre_i[r][k] = be1[k] + sum_c nf[r][c]*We1[c][k]
// pre_j[r][k] =          sum_c nf[r][c]*We1[128+c][k]
// api[r] = nf[r]·Wa[0:128] ; apj[r] = nf[r]·Wa[128:256]
__global__ __launch_bounds__(128)
void k_pre(const float* nf, const float* We1, const float* be1,
           const float* Wa, const float* mk,
           float* pre_i, float* pre_j, float* api, float* apj, float* sent) {
  int r = blockIdx.x, t = threadIdx.x;
  if (looks_bf16(mk)) {  // dtype sentinel: absmax ~555 => buffers are bf16
    if (r == 0) sent[t] = 555.f;
    return;
  }
  __shared__ float nfv[128];
  __shared__ float red[4];
  nfv[t] = nf[(size_t)r * 128 + t];
  __syncthreads();
  float s1 = be1[t], s2 = 0.f;
  for (int c = 0; c < 128; ++c) {
    float x = nfv[c];
    s1 += x * We1[c * 128 + t];
    s2 += x * We1[(128 + c) * 128 + t];
  }
  pre_i[(size_t)r * 128 + t] = s1;
  pre_j[(size_t)r * 128 + t] = s2;
  float t1 = nfv[t] * Wa[t];
  float t2 = nfv[t] * Wa[128 + t];
#pragma unroll
  for (int o = 32; o > 0; o >>= 1) { t1 += __shfl_down(t1, o); t2 += __shfl_down(t2, o); }
  if ((t & 63) == 0) { red[(t >> 6) * 2] = t1; red[(t >> 6) * 2 + 1] = t2; }
  __syncthreads();
  if (t == 0) { api[r] = red[0] + red[2]; apj[r] = red[1] + red[3]; }
}

// ---------------- kernel 2: pack We2 (fp32) into bf16 MFMA B-fragments ------
// bpack[((ks*8+nt)*64 + l)*8 + e] = bf16(We2[ks*32 + (l>>4)*8 + e][nt*16 + (l&15)])
__global__ __launch_bounds__(256)
void k_pack(const float* We2, ushort_t* bpack) {
  int t = blockIdx.x * 256 + threadIdx.x;
  if (t >= 2048) return;
  int ks = t >> 9, nt = (t >> 6) & 7, l = t & 63;
  int kb = ks * 32 + (l >> 4) * 8, col = nt * 16 + (l & 15);
#pragma unroll
  for (int e = 0; e < 8; ++e) bpack[t * 8 + e] = f2bf(We2[(kb + e) * 128 + col]);
}

// ---------------- kernel 3: edge MLP + attention + reductions ----------------
// grid 2048: block = (r = b*256+i, half of j). 128 threads = 2 waves.
// Phase 1: thread t owns edge row j = half*128 + t entirely.
__global__ __launch_bounds__(128)
void k_edge(const float* co, const float* efo, const float* mk,
            const float* We1, const float* be2, const float* Wa, const float* ba,
            const float* lnes, const float* lneb, const int* eidx,
            const float* pre_i, const float* pre_j, const float* api, const float* apj,
            const ushort_t* bpack, float* oute, float* nm2, float* cd2) {
  __shared__ __align__(16) ushort_t h1s[128 * 136];  // bf16 tile, 136-elem row stride
  __shared__ float wef[17 * 128];   // We1 rows 257..272 (ef) then row 256 (d2)
  __shared__ float preI[128];
  __shared__ float lns[128], lnb[128];
  __shared__ float attw[128];
  __shared__ float nmp[2][128];
  __shared__ float cred[2][3];

  if (looks_bf16(mk)) return;

  const int bx = blockIdx.x;
  const int r = bx >> 1, half = bx & 1;
  const int b = r >> 8;
  const int t = threadIdx.x;          // 0..127
  const int lane = t & 63, w = t >> 6;

  for (int q = t; q < 17 * 128; q += 128) {
    int e = q >> 7, c = q & 127;
    int row = (e < 16) ? (257 + e) : 256;
    wef[q] = We1[row * 128 + c];
  }
  preI[t] = pre_i[(size_t)r * 128 + t];
  lns[t] = lnes[t];
  lnb[t] = lneb[t];
  __syncthreads();

  // ---- phase 1 ----
  const int j = half * 128 + t;
  const int gj = b * 256 + j;

  float dx = co[r * 3 + 0] - co[gj * 3 + 0];
  float dy = co[r * 3 + 1] - co[gj * 3 + 1];
  float dz = co[r * 3 + 2] - co[gj * 3 + 2];
  float d2 = dx * dx + dy * dy + dz * dz;

  float efv[17];
  {
    const float* efp = efo + ((size_t)r * 256 + j) * 16;
    f32x4 e0 = *reinterpret_cast<const f32x4*>(efp);
    f32x4 e1 = *reinterpret_cast<const f32x4*>(efp + 4);
    f32x4 e2 = *reinterpret_cast<const f32x4*>(efp + 8);
    f32x4 e3 = *reinterpret_cast<const f32x4*>(efp + 12);
#pragma unroll
    for (int x = 0; x < 4; ++x) {
      efv[x] = e0[x]; efv[4 + x] = e1[x]; efv[8 + x] = e2[x]; efv[12 + x] = e3[x];
    }
  }
  efv[16] = d2;

  // attention + coord-dir contribution (thread-owned row)
  float a = api[r] + apj[gj] + ba[0] + d2 * Wa[256];
#pragma unroll
  for (int e = 0; e < 16; ++e) a += efv[e] * Wa[257 + e];
  float att = 1.f / (1.f + __expf(-a));
  float aw = att * (float)eidx[(size_t)r * 256 + j];
  attw[t] = aw * mk[r] * mk[gj];
  float invn = rsqrtf(d2 + 1e-8f);
  float c0 = dx * invn * aw, c1 = dy * invn * aw, c2 = dz * invn * aw;
#pragma unroll
  for (int o = 32; o > 0; o >>= 1) {
    c0 += __shfl_down(c0, o); c1 += __shfl_down(c1, o); c2 += __shfl_down(c2, o);
  }
  if (lane == 0) { cred[w][0] = c0; cred[w][1] = c1; cred[w][2] = c2; }

  // h1 row (128 channels), in-thread LN stats, bf16 store to own LDS row
  float s = 0.f, ss = 0.f;
  ushort_t* hrow = h1s + t * 136;
  const float* pjrow = pre_j + (size_t)gj * 128;
#pragma unroll
  for (int q = 0; q < 16; ++q) {
    f32x4 pj0 = *reinterpret_cast<const f32x4*>(pjrow + q * 8);
    f32x4 pj1 = *reinterpret_cast<const f32x4*>(pjrow + q * 8 + 4);
    float hv[8];
#pragma unroll
    for (int x = 0; x < 8; ++x)
      hv[x] = preI[q * 8 + x] + (x < 4 ? pj0[x] : pj1[x - 4]);
#pragma unroll
    for (int e = 0; e < 17; ++e) {
      float ev = efv[e];
#pragma unroll
      for (int x = 0; x < 8; ++x) hv[x] += ev * wef[e * 128 + q * 8 + x];
    }
    short8 pk;
#pragma unroll
    for (int x = 0; x < 8; ++x) {
      s += hv[x]; ss += hv[x] * hv[x];
      pk[x] = (short)f2bf(hv[x]);
    }
    *reinterpret_cast<short8*>(hrow + q * 8) = pk;
  }
  float mean = s * (1.f / 128.f);
  float var = fmaxf(ss * (1.f / 128.f) - mean * mean, 0.f);
  float rsv = rsqrtf(var + 1e-6f);
  // renormalize own row in place (same thread: no barrier needed)
#pragma unroll
  for (int q = 0; q < 16; ++q) {
    short8 pk = *reinterpret_cast<short8*>(hrow + q * 8);
    short8 op;
#pragma unroll
    for (int x = 0; x < 8; ++x) {
      float xv = bf2f((ushort_t)pk[x]);
      float gv = (xv - mean) * rsv * lns[q * 8 + x] + lnb[q * 8 + x];
      op[x] = (short)f2bf(fmaxf(gv, 0.f));
    }
    *reinterpret_cast<short8*>(hrow + q * 8) = op;
  }
  __syncthreads();

  if (t == 0) {
#pragma unroll
    for (int d = 0; d < 3; ++d)
      cd2[(size_t)(half * 1024 + r) * 3 + d] = cred[0][d] + cred[1][d];
  }

  // ---- phase 2: EM = H1LN @ We2 (+be2); store + att-weighted reduce ----
  f32x4 acc[4][8];
#pragma unroll
  for (int mt = 0; mt < 4; ++mt)
#pragma unroll
    for (int nt = 0; nt < 8; ++nt) acc[mt][nt] = (f32x4){0.f, 0.f, 0.f, 0.f};

  const short* h1p = reinterpret_cast<const short*>(h1s);
#pragma unroll
  for (int ks = 0; ks < 4; ++ks) {
    short8 bfr[8];
#pragma unroll
    for (int nt = 0; nt < 8; ++nt)
      bfr[nt] = *reinterpret_cast<const short8*>(bpack + (((ks * 8 + nt) * 64 + lane) * 8));
#pragma unroll
    for (int mt = 0; mt < 4; ++mt) {
      short8 afr = *reinterpret_cast<const short8*>(
          h1p + (w * 64 + mt * 16 + (lane & 15)) * 136 + ks * 32 + ((lane >> 4) * 8));
#pragma unroll
      for (int nt = 0; nt < 8; ++nt)
        acc[mt][nt] = __builtin_amdgcn_mfma_f32_16x16x32_bf16(afr, bfr[nt], acc[mt][nt], 0, 0, 0);
    }
  }

  float be2v[8], pnm[8];
#pragma unroll
  for (int nt = 0; nt < 8; ++nt) { be2v[nt] = be2[nt * 16 + (lane & 15)]; pnm[nt] = 0.f; }
  const size_t obase = ((size_t)r * 256 + half * 128) * 128;
#pragma unroll
  for (int mt = 0; mt < 4; ++mt)
#pragma unroll
    for (int r4 = 0; r4 < 4; ++r4) {
      int row = w * 64 + mt * 16 + (lane >> 4) * 4 + r4;
      float wgt = attw[row];
#pragma unroll
      for (int nt = 0; nt < 8; ++nt) {
        float val = acc[mt][nt][r4] + be2v[nt];
        oute[obase + (size_t)row * 128 + nt * 16 + (lane & 15)] = val;
        pnm[nt] += val * wgt;
      }
    }
#pragma unroll
  for (int nt = 0; nt < 8; ++nt) {
    pnm[nt] += __shfl_xor(pnm[nt], 16);
    pnm[nt] += __shfl_xor(pnm[nt], 32);
  }
  if (lane < 16)
#pragma unroll
    for (int nt = 0; nt < 8; ++nt) nmp[w][nt * 16 + lane] = pnm[nt];
  __syncthreads();
  nm2[(size_t)(half * 1024 + r) * 128 + t] = nmp[0][t] + nmp[1][t];
}

// ---------------- kernel 4: node MLP + coord MLP + outputs ----------------
__device__ __forceinline__ float bsum128(float v, float* red, int t) {
#pragma unroll
  for (int o = 32; o > 0; o >>= 1) v += __shfl_down(v, o);
  __syncthreads();
  if ((t & 63) == 0) red[t >> 6] = v;
  __syncthreads();
  return red[0] + red[1];
}

__global__ __launch_bounds__(128)
void k_node(const float* nf, const float* co, const float* mk,
            const float* Wn1, const float* bn1, const float* lnns, const float* lnnb,
            const float* Wn2, const float* bn2,
            const float* Wc1, const float* bc1, const float* lncs, const float* lncb,
            const float* Wc2, const float* bc2,
            const float* nm2, const float* cd2,
            float* out0, float* out1) {
  if (looks_bf16(mk)) return;
  int r = blockIdx.x, t = threadIdx.x;
  __shared__ float nin[256];
  __shared__ float hf[128];
  __shared__ float red[2];
  float nfv = nf[(size_t)r * 128 + t];
  float nmv = nm2[(size_t)r * 128 + t] + nm2[(size_t)(1024 + r) * 128 + t];
  nin[t] = nfv; nin[128 + t] = nmv;
  __syncthreads();
  float s1 = bn1[t];
  for (int c = 0; c < 256; ++c) s1 += nin[c] * Wn1[c * 128 + t];
  float mean = bsum128(s1, red, t) * (1.f / 128.f);
  float var = fmaxf(bsum128(s1 * s1, red, t) * (1.f / 128.f) - mean * mean, 0.f);
  float hv = (s1 - mean) * rsqrtf(var + 1e-6f) * lnns[t] + lnnb[t];
  hv = fmaxf(hv, 0.f);
  hf[t] = hv;
  __syncthreads();
  float o1 = bn2[t] + nfv;  // residual
  for (int c = 0; c < 128; ++c) o1 += hf[c] * Wn2[c * 128 + t];
  out0[(size_t)r * 128 + t] = o1;
  // coord MLP on node_messages
  float g = bc1[t];
  for (int c = 0; c < 128; ++c) g += nin[128 + c] * Wc1[c * 128 + t];
  float gm = bsum128(g, red, t) * (1.f / 128.f);
  float gv = fmaxf(bsum128(g * g, red, t) * (1.f / 128.f) - gm * gm, 0.f);
  float gh = fmaxf((g - gm) * rsqrtf(gv + 1e-6f) * lncs[t] + lncb[t], 0.f);
  float cm = bsum128(gh * Wc2[t], red, t) + bc2[0];
  if (t < 3) {
    float cd = cd2[(size_t)r * 3 + t] + cd2[(size_t)(1024 + r) * 3 + t];
    float nc = co[(size_t)r * 3 + t] + cd * cm * mk[r];
    out1[(size_t)r * 3 + t] = nc;
  }
}

extern "C" void kernel_launch(void* const* d_in, const int* in_sizes, int n_in,
                              void* d_out, int out_size, void* d_ws, size_t ws_size,
                              hipStream_t stream) {
  const float* nf   = (const float*)d_in[0];
  const float* co   = (const float*)d_in[1];
  const float* efo  = (const float*)d_in[2];
  const float* mk   = (const float*)d_in[3];
  const float* We1  = (const float*)d_in[4];
  const float* be1  = (const float*)d_in[5];
  const float* lnes = (const float*)d_in[6];
  const float* lneb = (const float*)d_in[7];
  const float* We2  = (const float*)d_in[8];
  const float* be2  = (const float*)d_in[9];
  const float* Wa   = (const float*)d_in[10];
  const float* ba   = (const float*)d_in[11];
  const float* Wn1  = (const float*)d_in[12];
  const float* bn1  = (const float*)d_in[13];
  const float* lnns = (const float*)d_in[14];
  const float* lnnb = (const float*)d_in[15];
  const float* Wn2  = (const float*)d_in[16];
  const float* bn2  = (const float*)d_in[17];
  const float* Wc1  = (const float*)d_in[18];
  const float* bc1  = (const float*)d_in[19];
  const float* lncs = (const float*)d_in[20];
  const float* lncb = (const float*)d_in[21];
  const float* Wc2  = (const float*)d_in[22];
  const float* bc2  = (const float*)d_in[23];
  const int* eidx   = (const int*)d_in[24];

  float* out0 = (float*)d_out;        // new_node_features [4,256,128]
  float* out1 = out0 + 131072;        // new_coordinates  [4,256,3]
  float* oute = out1 + 3072;          // new_edge_features [4,256,256,128]

  // workspace layout (floats): pre_i | pre_j | api | apj | nm2 | cd2 | bpack(bf16)
  const size_t need = (size_t)(131072 + 131072 + 1024 + 1024 + 262144 + 6144) * 4 + 16384 * 2;
  if (ws_size < need) {  // diagnostic sentinel: absmax ~777 => ws too small
    k_sent777<<<1, 128, 0, stream>>>(out0);
    return;
  }
  float* ws    = (float*)d_ws;
  float* pre_i = ws;
  float* pre_j = pre_i + 131072;
  float* api   = pre_j + 131072;
  float* apj   = api + 1024;
  float* nm2   = apj + 1024;
  float* cd2   = nm2 + 262144;
  ushort_t* bpack = (ushort_t*)(cd2 + 6144);

  k_pre<<<1024, 128, 0, stream>>>(nf, We1, be1, Wa, mk, pre_i, pre_j, api, apj, out0);
  k_pack<<<8, 256, 0, stream>>>(We2, bpack);
  k_edge<<<2048, 128, 0, stream>>>(co, efo, mk, We1, be2, Wa, ba, lnes, lneb, eidx,
                                   pre_i, pre_j, api, apj, bpack, oute, nm2, cd2);
  k_node<<<1024, 128, 0, stream>>>(nf, co, mk, Wn1, bn1, lnns, lnnb, Wn2, bn2,
                                   Wc1, bc1, lncs, lncb, Wc2, bc2, nm2, cd2, out0, out1);
}

// Round 4
// 93.025 us; speedup vs baseline: 1.1733x; 1.1733x over previous
//
#include <hip/hip_runtime.h>
#include <hip/hip_bf16.h>

// EGNN layer, MI355X. B=4, N=256, H=128, E=16, EIN=273. All I/O float32.
// h1 = pre_i(i) + pre_j(j) + d2*w_d2 + ef@Wef + be1 (layer-1 GEMM collapses to
// per-node precompute + 17x128 per-edge assembly); layer-2 128x128 GEMM via
// mfma_f32_16x16x32_bf16 (h1, We2 rounded to bf16 internally). k_edge: 256
// threads / 4 waves per 128-row tile, two threads per row (64 channels each),
// LN stats merged via one LDS exchange. Deterministic tree reductions only.

typedef unsigned short ushort_t;
typedef __attribute__((ext_vector_type(8))) short short8;
typedef __attribute__((ext_vector_type(4))) float f32x4;

__device__ __forceinline__ ushort_t f2bf(float f) {
  unsigned int x = __builtin_bit_cast(unsigned int, f);
  x += 0x7fffu + ((x >> 16) & 1u);
  return (ushort_t)(x >> 16);
}

__global__ void k_sent777(float* out0) { out0[threadIdx.x] = 777.f; }

// ---------------- kernel 1: per-node pre-projections ----------------
__global__ __launch_bounds__(128)
void k_pre(const float* nf, const float* We1, const float* be1,
           const float* Wa, float* pre_i, float* pre_j, float* api, float* apj) {
  int r = blockIdx.x, t = threadIdx.x;
  __shared__ float nfv[128];
  __shared__ float red[4];
  nfv[t] = nf[(size_t)r * 128 + t];
  __syncthreads();
  float s1 = be1[t], s2 = 0.f;
  for (int c = 0; c < 128; ++c) {
    float x = nfv[c];
    s1 += x * We1[c * 128 + t];
    s2 += x * We1[(128 + c) * 128 + t];
  }
  pre_i[(size_t)r * 128 + t] = s1;
  pre_j[(size_t)r * 128 + t] = s2;
  float t1 = nfv[t] * Wa[t];
  float t2 = nfv[t] * Wa[128 + t];
#pragma unroll
  for (int o = 32; o > 0; o >>= 1) { t1 += __shfl_down(t1, o); t2 += __shfl_down(t2, o); }
  if ((t & 63) == 0) { red[(t >> 6) * 2] = t1; red[(t >> 6) * 2 + 1] = t2; }
  __syncthreads();
  if (t == 0) { api[r] = red[0] + red[2]; apj[r] = red[1] + red[3]; }
}

// ---------------- kernel 2: pack We2 (fp32) into bf16 MFMA B-fragments ------
// bpack[((ks*8+nt)*64 + l)*8 + e] = bf16(We2[ks*32 + (l>>4)*8 + e][nt*16 + (l&15)])
__global__ __launch_bounds__(256)
void k_pack(const float* We2, ushort_t* bpack) {
  int t = blockIdx.x * 256 + threadIdx.x;
  if (t >= 2048) return;
  int ks = t >> 9, nt = (t >> 6) & 7, l = t & 63;
  int kb = ks * 32 + (l >> 4) * 8, col = nt * 16 + (l & 15);
#pragma unroll
  for (int e = 0; e < 8; ++e) bpack[t * 8 + e] = f2bf(We2[(kb + e) * 128 + col]);
}

// ---------------- kernel 3: edge MLP + attention + reductions ----------------
// grid 2048: block = (r = b*256+i, half of j). 256 threads = 4 waves.
// Phase 1: thread t handles row jr = t&127, channels (t>>7)*64..+63.
__global__ __launch_bounds__(256)
void k_edge(const float* co, const float* efo, const float* mk,
            const float* We1, const float* be2, const float* Wa, const float* ba,
            const float* lnes, const float* lneb, const int* eidx,
            const float* pre_i, const float* pre_j, const float* api, const float* apj,
            const ushort_t* bpack, float* oute, float* nm2, float* cd2) {
  __shared__ __align__(16) ushort_t h1s[128 * 136];  // bf16 tile, 136-elem row stride
  __shared__ float wef[17 * 128];   // We1 rows 257..272 (ef) then row 256 (d2)
  __shared__ float lns[128], lnb[128];
  __shared__ float attw[128];
  __shared__ float lnS[256], lnSS[256];
  __shared__ float nmp[4][128];
  __shared__ float cred[2][3];

  const int bx = blockIdx.x;
  const int r = bx >> 1, half = bx & 1;
  const int b = r >> 8;
  const int t = threadIdx.x;          // 0..255
  const int lane = t & 63, w = t >> 6;

  for (int q = t; q < 17 * 128; q += 256) {
    int e = q >> 7, c = q & 127;
    int row = (e < 16) ? (257 + e) : 256;
    wef[q] = We1[row * 128 + c];
  }
  if (t < 128) { lns[t] = lnes[t]; }
  else { lnb[t - 128] = lneb[t - 128]; }
  __syncthreads();

  // ---- phase 1 ----
  const int jr = t & 127, ch = t >> 7;  // row in tile, channel-half
  const int j = half * 128 + jr;
  const int gj = b * 256 + j;

  float dx = co[r * 3 + 0] - co[gj * 3 + 0];
  float dy = co[r * 3 + 1] - co[gj * 3 + 1];
  float dz = co[r * 3 + 2] - co[gj * 3 + 2];
  float d2 = dx * dx + dy * dy + dz * dz;

  float efv[17];
  {
    const float* efp = efo + ((size_t)r * 256 + j) * 16;
    f32x4 e0 = *reinterpret_cast<const f32x4*>(efp);
    f32x4 e1 = *reinterpret_cast<const f32x4*>(efp + 4);
    f32x4 e2 = *reinterpret_cast<const f32x4*>(efp + 8);
    f32x4 e3 = *reinterpret_cast<const f32x4*>(efp + 12);
#pragma unroll
    for (int x = 0; x < 4; ++x) {
      efv[x] = e0[x]; efv[4 + x] = e1[x]; efv[8 + x] = e2[x]; efv[12 + x] = e3[x];
    }
  }
  efv[16] = d2;

  if (ch == 0) {  // waves 0,1: attention + coord-dir for own row
    float a = api[r] + apj[gj] + ba[0] + d2 * Wa[256];
#pragma unroll
    for (int e = 0; e < 16; ++e) a += efv[e] * Wa[257 + e];
    float att = 1.f / (1.f + __expf(-a));
    float aw = att * (float)eidx[(size_t)r * 256 + j];
    attw[jr] = aw * mk[r] * mk[gj];
    float invn = rsqrtf(d2 + 1e-8f);
    float c0 = dx * invn * aw, c1 = dy * invn * aw, c2 = dz * invn * aw;
#pragma unroll
    for (int o = 32; o > 0; o >>= 1) {
      c0 += __shfl_down(c0, o); c1 += __shfl_down(c1, o); c2 += __shfl_down(c2, o);
    }
    if (lane == 0) { cred[w][0] = c0; cred[w][1] = c1; cred[w][2] = c2; }
  }

  // h1 half-row (64 channels): fp32 regs, partial LN stats
  const int cbase = ch * 64;
  const f32x4* pi4 = reinterpret_cast<const f32x4*>(pre_i + (size_t)r * 128 + cbase);
  const f32x4* pj4 = reinterpret_cast<const f32x4*>(pre_j + (size_t)gj * 128 + cbase);
  const f32x4* wef4 = reinterpret_cast<const f32x4*>(wef);
  float h[64];
  float s = 0.f, ss = 0.f;
#pragma unroll
  for (int c4 = 0; c4 < 16; ++c4) {
    f32x4 v = pi4[c4] + pj4[c4];
#pragma unroll
    for (int e = 0; e < 17; ++e) v += efv[e] * wef4[e * 32 + (cbase >> 2) + c4];
#pragma unroll
    for (int x = 0; x < 4; ++x) { h[c4 * 4 + x] = v[x]; s += v[x]; ss += v[x] * v[x]; }
  }
  lnS[t] = s; lnSS[t] = ss;
  __syncthreads();
  float st = s + lnS[t ^ 128], sst = ss + lnSS[t ^ 128];
  float mean = st * (1.f / 128.f);
  float var = fmaxf(sst * (1.f / 128.f) - mean * mean, 0.f);
  float rsv = rsqrtf(var + 1e-6f);
  ushort_t* hrow = h1s + jr * 136 + cbase;
#pragma unroll
  for (int q8 = 0; q8 < 8; ++q8) {
    short8 pk;
#pragma unroll
    for (int x = 0; x < 8; ++x) {
      int c = q8 * 8 + x;
      float gv = (h[c] - mean) * rsv * lns[cbase + c] + lnb[cbase + c];
      pk[x] = (short)f2bf(fmaxf(gv, 0.f));
    }
    *reinterpret_cast<short8*>(hrow + q8 * 8) = pk;
  }
  __syncthreads();

  if (t == 0) {
#pragma unroll
    for (int d = 0; d < 3; ++d)
      cd2[(size_t)(half * 1024 + r) * 3 + d] = cred[0][d] + cred[1][d];
  }

  // ---- phase 2: EM = H1LN @ We2 (+be2); store + att-weighted reduce ----
  f32x4 acc[2][8];
#pragma unroll
  for (int mt = 0; mt < 2; ++mt)
#pragma unroll
    for (int nt = 0; nt < 8; ++nt) acc[mt][nt] = (f32x4){0.f, 0.f, 0.f, 0.f};

  const short* h1p = reinterpret_cast<const short*>(h1s);
#pragma unroll
  for (int ks = 0; ks < 4; ++ks) {
    short8 bfr[8];
#pragma unroll
    for (int nt = 0; nt < 8; ++nt)
      bfr[nt] = *reinterpret_cast<const short8*>(bpack + (((ks * 8 + nt) * 64 + lane) * 8));
#pragma unroll
    for (int mt = 0; mt < 2; ++mt) {
      short8 afr = *reinterpret_cast<const short8*>(
          h1p + (w * 32 + mt * 16 + (lane & 15)) * 136 + ks * 32 + ((lane >> 4) * 8));
#pragma unroll
      for (int nt = 0; nt < 8; ++nt)
        acc[mt][nt] = __builtin_amdgcn_mfma_f32_16x16x32_bf16(afr, bfr[nt], acc[mt][nt], 0, 0, 0);
    }
  }

  float be2v[8], pnm[8];
#pragma unroll
  for (int nt = 0; nt < 8; ++nt) { be2v[nt] = be2[nt * 16 + (lane & 15)]; pnm[nt] = 0.f; }
  const size_t obase = ((size_t)r * 256 + half * 128) * 128;
#pragma unroll
  for (int mt = 0; mt < 2; ++mt)
#pragma unroll
    for (int r4 = 0; r4 < 4; ++r4) {
      int row = w * 32 + mt * 16 + (lane >> 4) * 4 + r4;
      float wgt = attw[row];
#pragma unroll
      for (int nt = 0; nt < 8; ++nt) {
        float val = acc[mt][nt][r4] + be2v[nt];
        oute[obase + (size_t)row * 128 + nt * 16 + (lane & 15)] = val;
        pnm[nt] += val * wgt;
      }
    }
#pragma unroll
  for (int nt = 0; nt < 8; ++nt) {
    pnm[nt] += __shfl_xor(pnm[nt], 16);
    pnm[nt] += __shfl_xor(pnm[nt], 32);
  }
  if (lane < 16)
#pragma unroll
    for (int nt = 0; nt < 8; ++nt) nmp[w][nt * 16 + lane] = pnm[nt];
  __syncthreads();
  if (t < 128)
    nm2[(size_t)(half * 1024 + r) * 128 + t] = nmp[0][t] + nmp[1][t] + nmp[2][t] + nmp[3][t];
}

// ---------------- kernel 4: node MLP + coord MLP + outputs ----------------
__device__ __forceinline__ float bsum128(float v, float* red, int t) {
#pragma unroll
  for (int o = 32; o > 0; o >>= 1) v += __shfl_down(v, o);
  __syncthreads();
  if ((t & 63) == 0) red[t >> 6] = v;
  __syncthreads();
  return red[0] + red[1];
}

__global__ __launch_bounds__(128)
void k_node(const float* nf, const float* co, const float* mk,
            const float* Wn1, const float* bn1, const float* lnns, const float* lnnb,
            const float* Wn2, const float* bn2,
            const float* Wc1, const float* bc1, const float* lncs, const float* lncb,
            const float* Wc2, const float* bc2,
            const float* nm2, const float* cd2,
            float* out0, float* out1) {
  int r = blockIdx.x, t = threadIdx.x;
  __shared__ float nin[256];
  __shared__ float hf[128];
  __shared__ float red[2];
  float nfv = nf[(size_t)r * 128 + t];
  float nmv = nm2[(size_t)r * 128 + t] + nm2[(size_t)(1024 + r) * 128 + t];
  nin[t] = nfv; nin[128 + t] = nmv;
  __syncthreads();
  float s1 = bn1[t];
  for (int c = 0; c < 256; ++c) s1 += nin[c] * Wn1[c * 128 + t];
  float mean = bsum128(s1, red, t) * (1.f / 128.f);
  float var = fmaxf(bsum128(s1 * s1, red, t) * (1.f / 128.f) - mean * mean, 0.f);
  float hv = (s1 - mean) * rsqrtf(var + 1e-6f) * lnns[t] + lnnb[t];
  hv = fmaxf(hv, 0.f);
  hf[t] = hv;
  __syncthreads();
  float o1 = bn2[t] + nfv;  // residual
  for (int c = 0; c < 128; ++c) o1 += hf[c] * Wn2[c * 128 + t];
  out0[(size_t)r * 128 + t] = o1;
  // coord MLP on node_messages
  float g = bc1[t];
  for (int c = 0; c < 128; ++c) g += nin[128 + c] * Wc1[c * 128 + t];
  float gm = bsum128(g, red, t) * (1.f / 128.f);
  float gv = fmaxf(bsum128(g * g, red, t) * (1.f / 128.f) - gm * gm, 0.f);
  float gh = fmaxf((g - gm) * rsqrtf(gv + 1e-6f) * lncs[t] + lncb[t], 0.f);
  float cm = bsum128(gh * Wc2[t], red, t) + bc2[0];
  if (t < 3) {
    float cd = cd2[(size_t)r * 3 + t] + cd2[(size_t)(1024 + r) * 3 + t];
    float nc = co[(size_t)r * 3 + t] + cd * cm * mk[r];
    out1[(size_t)r * 3 + t] = nc;
  }
}

extern "C" void kernel_launch(void* const* d_in, const int* in_sizes, int n_in,
                              void* d_out, int out_size, void* d_ws, size_t ws_size,
                              hipStream_t stream) {
  const float* nf   = (const float*)d_in[0];
  const float* co   = (const float*)d_in[1];
  const float* efo  = (const float*)d_in[2];
  const float* mk   = (const float*)d_in[3];
  const float* We1  = (const float*)d_in[4];
  const float* be1  = (const float*)d_in[5];
  const float* lnes = (const float*)d_in[6];
  const float* lneb = (const float*)d_in[7];
  const float* We2  = (const float*)d_in[8];
  const float* be2  = (const float*)d_in[9];
  const float* Wa   = (const float*)d_in[10];
  const float* ba   = (const float*)d_in[11];
  const float* Wn1  = (const float*)d_in[12];
  const float* bn1  = (const float*)d_in[13];
  const float* lnns = (const float*)d_in[14];
  const float* lnnb = (const float*)d_in[15];
  const float* Wn2  = (const float*)d_in[16];
  const float* bn2  = (const float*)d_in[17];
  const float* Wc1  = (const float*)d_in[18];
  const float* bc1  = (const float*)d_in[19];
  const float* lncs = (const float*)d_in[20];
  const float* lncb = (const float*)d_in[21];
  const float* Wc2  = (const float*)d_in[22];
  const float* bc2  = (const float*)d_in[23];
  const int* eidx   = (const int*)d_in[24];

  float* out0 = (float*)d_out;        // new_node_features [4,256,128]
  float* out1 = out0 + 131072;        // new_coordinates  [4,256,3]
  float* oute = out1 + 3072;          // new_edge_features [4,256,256,128]

  const size_t need = (size_t)(131072 + 131072 + 1024 + 1024 + 262144 + 6144) * 4 + 16384 * 2;
  if (ws_size < need) {  // diagnostic sentinel: absmax ~777 => ws too small
    k_sent777<<<1, 128, 0, stream>>>(out0);
    return;
  }
  float* ws    = (float*)d_ws;
  float* pre_i = ws;
  float* pre_j = pre_i + 131072;
  float* api   = pre_j + 131072;
  float* apj   = api + 1024;
  float* nm2   = apj + 1024;
  float* cd2   = nm2 + 262144;
  ushort_t* bpack = (ushort_t*)(cd2 + 6144);

  k_pre<<<1024, 128, 0, stream>>>(nf, We1, be1, Wa, pre_i, pre_j, api, apj);
  k_pack<<<8, 256, 0, stream>>>(We2, bpack);
  k_edge<<<2048, 256, 0, stream>>>(co, efo, mk, We1, be2, Wa, ba, lnes, lneb, eidx,
                                   pre_i, pre_j, api, apj, bpack, oute, nm2, cd2);
  k_node<<<1024, 128, 0, stream>>>(nf, co, mk, Wn1, bn1, lnns, lnnb, Wn2, bn2,
                                   Wc1, bc1, lncs, lncb, Wc2, bc2, nm2, cd2, out0, out1);
}